// Round 4
// baseline (272.518 us; speedup 1.0000x reference)
//
#include <hip/hip_runtime.h>
#include <hip/hip_bf16.h>
#include <stdint.h>

// EuclideanDeconf: x[B,D] fp32, W[C,D] fp32 -> out[B,C] fp32
// out = (2/D)*x.W^T - ||x||^2/D - ||w||^2/D
#define B_ROWS 16384
#define D_DIM  1024
#define C_DIM  2048
#define KT32   (D_DIM / 32)    // 32 K-steps of 32 (= pack chunk granularity)
#define MT_TOT (B_ROWS / 16)   // 1024 m-tiles
#define NT_TOT (C_DIM  / 16)   // 128  n-tiles

typedef short bf16x8 __attribute__((ext_vector_type(8)));   // 8 bf16 = 4 VGPRs
typedef float f32x4  __attribute__((ext_vector_type(4)));

#define AS1 __attribute__((address_space(1)))
#define AS3 __attribute__((address_space(3)))
#define BARRIER __builtin_amdgcn_s_barrier()
#define LGKM0 asm volatile("s_waitcnt lgkmcnt(0)")
#define VMCNT(n) asm volatile("s_waitcnt vmcnt(" #n ")" ::: "memory")
#define PRIO1 __builtin_amdgcn_s_setprio(1)
#define PRIO0 __builtin_amdgcn_s_setprio(0)

// ---------------------------------------------------------------------------
// pack_norm (verified R3, unchanged): fp32 -> bf16 in MFMA fragment order.
// Chunk (tile, ktc) = 1 KB = 64 lanes x 16 B; lane l holds row = tile*16+(l&15),
// k = ktc*32 + (l>>4)*8 .. +7 — exact A/B operand layout of
// mfma_f32_16x16x32_bf16. One wave per chunk; norms via atomicAdd.
// ---------------------------------------------------------------------------
__global__ __launch_bounds__(256) void pack_norm(
        const float* __restrict__ x, const float* __restrict__ W,
        ushort* __restrict__ Apk, ushort* __restrict__ Bpk,
        float* __restrict__ x2, float* __restrict__ w2) {
    int chunk = blockIdx.x * 4 + (threadIdx.x >> 6);
    const int lane = threadIdx.x & 63;
    const int XCH = MT_TOT * KT32;              // 32768 x-chunks
    const float* src; ushort* dst; float* norm;
    if (chunk < XCH) { src = x; dst = Apk; norm = x2; }
    else             { src = W; dst = Bpk; norm = w2; chunk -= XCH; }
    const int tile = chunk >> 5;                // /KT32
    const int kt   = chunk & 31;

    const int row = tile * 16 + (lane & 15);
    const int k0  = kt * 32 + (lane >> 4) * 8;
    const float4 v0 = *(const float4*)(src + (size_t)row * D_DIM + k0);
    const float4 v1 = *(const float4*)(src + (size_t)row * D_DIM + k0 + 4);
    float s = v0.x*v0.x + v0.y*v0.y + v0.z*v0.z + v0.w*v0.w
            + v1.x*v1.x + v1.y*v1.y + v1.z*v1.z + v1.w*v1.w;

    ushort u[8]; __hip_bfloat16 h;
    h = __float2bfloat16(v0.x); u[0] = *(const ushort*)&h;
    h = __float2bfloat16(v0.y); u[1] = *(const ushort*)&h;
    h = __float2bfloat16(v0.z); u[2] = *(const ushort*)&h;
    h = __float2bfloat16(v0.w); u[3] = *(const ushort*)&h;
    h = __float2bfloat16(v1.x); u[4] = *(const ushort*)&h;
    h = __float2bfloat16(v1.y); u[5] = *(const ushort*)&h;
    h = __float2bfloat16(v1.z); u[6] = *(const ushort*)&h;
    h = __float2bfloat16(v1.w); u[7] = *(const ushort*)&h;
    *(bf16x8*)(dst + ((size_t)chunk * 64 + lane) * 8) = *(const bf16x8*)u;

    s += __shfl_xor(s, 16, 64);
    s += __shfl_xor(s, 32, 64);
    if (lane < 16) atomicAdd(norm + tile * 16 + lane, s * (1.0f / (float)D_DIM));
}

// ---------------------------------------------------------------------------
// gemm_areg (R7): R2 geometry (128x128 tile, 4 waves 2x2, BK=32, 3 blocks/CU)
// but A BYPASSES LDS: packed chunks are fragment-ordered, so a per-lane
// global_load_dwordx4 at lane*16B of an A-chunk IS the wave's MFMA A-operand.
// A-frags double-buffered in regs (aE/aO, static names per rule #20), loaded
// ONE step ahead (~600 cy cover vs ~200 cy L2 latency; A panel is L2-warm:
// 16 bn-blocks of one bm share an XCD via slab swizzle). B stays in LDS,
// triple-buffered: 3 x 8 KB = 24 KB total -> 3 blocks/CU with headroom.
// Per K-step per wave: 4 ds_read_b128 (B, conflict-free) + 4 global A-loads
// + 2 global_load_lds B-stage (kt+2) + vmcnt(6) (one full step back, never
// 0) + barrier + 16 MFMA (setprio) + barrier. LDS pipe per CU-instance
// drops 510 -> ~254 cy; MFMA (310 cy) becomes the binding pipe.
// Rotation/barrier discipline bit-identical to verified R2.
// Epilogue: out = acc*(2/D) - x2[row] - w2[col]  (C/D layout per m89).
// ---------------------------------------------------------------------------
__global__ __launch_bounds__(256, 3) void gemm_areg(
        const ushort* __restrict__ Apk, const ushort* __restrict__ Bpk,
        const float* __restrict__ x2, const float* __restrict__ w2,
        float* __restrict__ out) {
    __shared__ ushort Bs[3 * 4096];   // 24 KB: 3 bufs x 8 B-tiles x 512

    const int tid  = threadIdx.x;
    const int lane = tid & 63;
    const int wv   = tid >> 6;          // [0,4)

    const int wid = (blockIdx.x & 7) * 256 + (blockIdx.x >> 3);  // XCD slab
    const int bm  = wid >> 4;           // [0,128)
    const int bn  = wid & 15;           // [0,16)

    // global bases (ushort units); chunk (tile,ktc) at (tile*KT32+ktc)*512
    const ushort* aSrc = Apk + ((size_t)(bm * 8) * KT32) * 512 + lane * 8;
    const ushort* bSrc = Bpk + ((size_t)(bn * 8) * KT32) * 512 + lane * 8;

    // A: wave owns m-tiles (wv>>1)*4 + 0..3, read DIRECT to registers
    const int tA = (wv >> 1) * 4;
    // B: wave reads tiles (wv&1)*4 + 0..3 from LDS
    const ushort* bRd = Bs + (wv & 1) * 2048 + lane * 8;

#define GLL(src, dst) __builtin_amdgcn_global_load_lds( \
        (const AS1 void*)(src), (AS3 void*)(dst), 16, 0, 0)
    // wave stages B tiles {wv, wv+4} for K-step ktc into buffer at bO
#define STAGEB(ktc, bO) do { \
    GLL(bSrc + ((size_t)(wv)     * KT32 + (ktc)) * 512, Bs + (bO) + (wv)     * 512); \
    GLL(bSrc + ((size_t)(wv + 4) * KT32 + (ktc)) * 512, Bs + (bO) + (wv + 4) * 512); \
  } while (0)
    // load wave's 4 A-fragments for K-step ktc into named regs (rule #20)
#define LOADA(AR, ktc) do { \
    AR##0 = *(const bf16x8*)(aSrc + ((size_t)(tA + 0) * KT32 + (ktc)) * 512); \
    AR##1 = *(const bf16x8*)(aSrc + ((size_t)(tA + 1) * KT32 + (ktc)) * 512); \
    AR##2 = *(const bf16x8*)(aSrc + ((size_t)(tA + 2) * KT32 + (ktc)) * 512); \
    AR##3 = *(const bf16x8*)(aSrc + ((size_t)(tA + 3) * KT32 + (ktc)) * 512); \
  } while (0)

    f32x4 acc[4][4];
    #pragma unroll
    for (int mi = 0; mi < 4; ++mi)
        #pragma unroll
        for (int ni = 0; ni < 4; ++ni)
            acc[mi][ni] = (f32x4){0.f, 0.f, 0.f, 0.f};

    bf16x8 aE0, aE1, aE2, aE3, aO0, aO1, aO2, aO3;

    // ---- prologue: A(0)->aE, B(0)->buf0, B(1)->buf1 ----
    LOADA(aE, 0);        // 4 VMEM
    STAGEB(0, 0);        // 2 VMEM
    STAGEB(1, 4096);     // 2 VMEM
    VMCNT(2);            // A(0)+B(0) landed; B(1)'s 2 stay in flight
    BARRIER;

    int cB = 0, nB = 4096, sB = 8192;   // rotating B-buffer offsets (ushorts)

    // one K-step; AC = current A frags, AN = next (loaded for kt+1)
#define STEP(kt, AC, AN) do { \
    bf16x8 b0_ = *(const bf16x8*)(bRd + cB);                                  \
    bf16x8 b1_ = *(const bf16x8*)(bRd + cB + 512);                            \
    bf16x8 b2_ = *(const bf16x8*)(bRd + cB + 1024);                           \
    bf16x8 b3_ = *(const bf16x8*)(bRd + cB + 1536);                           \
    LOADA(AN, ((kt) + 1) & 31);                                               \
    STAGEB(((kt) + 2) & 31, sB);                                              \
    VMCNT(6);   /* prev step's 4A+2B retired; this step's 6 in flight */      \
    BARRIER;    /* all waves' B(kt+1) writes visible; buffers consistent */   \
    LGKM0;                                                                    \
    PRIO1;                                                                    \
    acc[0][0] = __builtin_amdgcn_mfma_f32_16x16x32_bf16(AC##0, b0_, acc[0][0], 0, 0, 0); \
    acc[0][1] = __builtin_amdgcn_mfma_f32_16x16x32_bf16(AC##0, b1_, acc[0][1], 0, 0, 0); \
    acc[0][2] = __builtin_amdgcn_mfma_f32_16x16x32_bf16(AC##0, b2_, acc[0][2], 0, 0, 0); \
    acc[0][3] = __builtin_amdgcn_mfma_f32_16x16x32_bf16(AC##0, b3_, acc[0][3], 0, 0, 0); \
    acc[1][0] = __builtin_amdgcn_mfma_f32_16x16x32_bf16(AC##1, b0_, acc[1][0], 0, 0, 0); \
    acc[1][1] = __builtin_amdgcn_mfma_f32_16x16x32_bf16(AC##1, b1_, acc[1][1], 0, 0, 0); \
    acc[1][2] = __builtin_amdgcn_mfma_f32_16x16x32_bf16(AC##1, b2_, acc[1][2], 0, 0, 0); \
    acc[1][3] = __builtin_amdgcn_mfma_f32_16x16x32_bf16(AC##1, b3_, acc[1][3], 0, 0, 0); \
    acc[2][0] = __builtin_amdgcn_mfma_f32_16x16x32_bf16(AC##2, b0_, acc[2][0], 0, 0, 0); \
    acc[2][1] = __builtin_amdgcn_mfma_f32_16x16x32_bf16(AC##2, b1_, acc[2][1], 0, 0, 0); \
    acc[2][2] = __builtin_amdgcn_mfma_f32_16x16x32_bf16(AC##2, b2_, acc[2][2], 0, 0, 0); \
    acc[2][3] = __builtin_amdgcn_mfma_f32_16x16x32_bf16(AC##2, b3_, acc[2][3], 0, 0, 0); \
    acc[3][0] = __builtin_amdgcn_mfma_f32_16x16x32_bf16(AC##3, b0_, acc[3][0], 0, 0, 0); \
    acc[3][1] = __builtin_amdgcn_mfma_f32_16x16x32_bf16(AC##3, b1_, acc[3][1], 0, 0, 0); \
    acc[3][2] = __builtin_amdgcn_mfma_f32_16x16x32_bf16(AC##3, b2_, acc[3][2], 0, 0, 0); \
    acc[3][3] = __builtin_amdgcn_mfma_f32_16x16x32_bf16(AC##3, b3_, acc[3][3], 0, 0, 0); \
    PRIO0;                                                                    \
    BARRIER;    /* reads of buf(cur) done before anyone stages into it */     \
    int t_ = cB; cB = nB; nB = sB; sB = t_;                                   \
  } while (0)

    for (int kt = 0; kt < KT32; kt += 2) {
        STEP(kt,     aE, aO);
        STEP(kt + 1, aO, aE);
    }

    // ---- epilogue: C/D layout col=lane&15, row=(lane>>4)*4+reg (m89) ----
    const float scale = 2.0f / (float)D_DIM;
    const int rsel = lane & 15;
    const int quad = lane >> 4;
    const int mT0  = bm * 8 + tA;
    const int nT0  = bn * 8 + (wv & 1) * 4;
    const int row0 = mT0 * 16 + quad * 4;
    const int col0 = nT0 * 16 + rsel;

    float x2r[4][4];
    #pragma unroll
    for (int mi = 0; mi < 4; ++mi)
        #pragma unroll
        for (int r = 0; r < 4; ++r)
            x2r[mi][r] = x2[row0 + mi * 16 + r];

    #pragma unroll
    for (int ni = 0; ni < 4; ++ni) {
        const int c = col0 + ni * 16;
        const float wc = w2[c];
        #pragma unroll
        for (int mi = 0; mi < 4; ++mi) {
            #pragma unroll
            for (int r = 0; r < 4; ++r) {
                const int rr = row0 + mi * 16 + r;
                out[(size_t)rr * C_DIM + c] = acc[mi][ni][r] * scale - x2r[mi][r] - wc;
            }
        }
    }
#undef STEP
#undef LOADA
#undef STAGEB
#undef GLL
}

// ---------------------------------------------------------------------------
extern "C" void kernel_launch(void* const* d_in, const int* in_sizes, int n_in,
                              void* d_out, int out_size, void* d_ws, size_t ws_size,
                              hipStream_t stream) {
    const float* x = (const float*)d_in[0];   // [B, D] fp32
    const float* W = (const float*)d_in[1];   // [C, D] fp32
    float* out = (float*)d_out;               // [B, C] fp32

    // ws: Apk (32 MB bf16 packed) | Bpk (4 MB) | x2 (64 KB) | w2 (8 KB)
    char* ws = (char*)d_ws;
    ushort* Apk = (ushort*)ws;
    ushort* Bpk = (ushort*)(ws + (size_t)B_ROWS * D_DIM * sizeof(ushort));
    float*  x2  = (float*)(ws + (size_t)(B_ROWS + C_DIM) * D_DIM * sizeof(ushort));
    float*  w2  = x2 + B_ROWS;

    hipMemsetAsync(x2, 0, (B_ROWS + C_DIM) * sizeof(float), stream);

    pack_norm<<<(MT_TOT * KT32 + NT_TOT * KT32) / 4, 256, 0, stream>>>(
        x, W, Apk, Bpk, x2, w2);

    gemm_areg<<<(B_ROWS / 128) * (C_DIM / 128), 256, 0, stream>>>(
        Apk, Bpk, x2, w2, out);
}

// Round 5
// 265.163 us; speedup vs baseline: 1.0277x; 1.0277x over previous
//
#include <hip/hip_runtime.h>
#include <hip/hip_bf16.h>
#include <stdint.h>

// EuclideanDeconf: x[B,D] fp32, W[C,D] fp32 -> out[B,C] fp32
// out = (2/D)*x.W^T - ||x||^2/D - ||w||^2/D
#define B_ROWS 16384
#define D_DIM  1024
#define C_DIM  2048
#define KT32   (D_DIM / 32)    // 32 K-steps of 32 (= pack chunk granularity)
#define MT_TOT (B_ROWS / 16)   // 1024 m-tiles
#define NT_TOT (C_DIM  / 16)   // 128  n-tiles

typedef short bf16x8 __attribute__((ext_vector_type(8)));   // 8 bf16 = 4 VGPRs
typedef float f32x4  __attribute__((ext_vector_type(4)));
typedef unsigned short us4 __attribute__((ext_vector_type(4)));  // 8B, 8B-aligned

#define AS1 __attribute__((address_space(1)))
#define AS3 __attribute__((address_space(3)))
#define BARRIER __builtin_amdgcn_s_barrier()
#define LGKM0 asm volatile("s_waitcnt lgkmcnt(0)")
#define VMCNT(n) asm volatile("s_waitcnt vmcnt(" #n ")" ::: "memory")
#define PRIO1 __builtin_amdgcn_s_setprio(1)
#define PRIO0 __builtin_amdgcn_s_setprio(0)

// ---------------------------------------------------------------------------
// pack_norm2 (R8): the old pack_norm read 16-row-scattered 16B segments
// (transaction-bound, ~85 µs measured by dispatch accounting in R1).
// New structure: one block per 16-row tile (64 KB fp32, CONTIGUOUS).
//   iter i (=row i): thread t reads float4 at k=4t  -> coalesced 4 KB/iter
//   convert to 4 bf16, ds_write 8B at pack position, slot XOR-swizzled by
//   (kt&7) -> write phase hits all 32 banks exactly 4x (4-cy optimum),
//   readout (slot = lane^(kt&7)) is a permutation of linear -> conflict-free.
//   norms: 6-step shfl_xor wave reduce, lane0 atomicAdd (4 adds/row).
// After barrier: wave w streams chunks w*8..w*8+7 LDS->global as contiguous
// 1 KB bf16x8 stores. Both global sides now run at HBM rate (~20 µs total).
// Chunk (tile,kt) layout in global is UNCHANGED: byte p*16 holds 8 bf16 of
// (row=tile*16+(p&15), k=kt*32+(p>>4)*8..+7) — gemm_tb consumes it as before.
// ---------------------------------------------------------------------------
__global__ __launch_bounds__(256) void pack_norm2(
        const float* __restrict__ x, const float* __restrict__ W,
        ushort* __restrict__ Apk, ushort* __restrict__ Bpk,
        float* __restrict__ x2, float* __restrict__ w2) {
    __shared__ ushort L[KT32 * 512];   // 32 KB, packed+swizzled bf16 tile

    int tile = blockIdx.x;
    const float* src; ushort* dst; float* norm;
    if (tile < MT_TOT) { src = x; dst = Apk; norm = x2; }
    else               { src = W; dst = Bpk; norm = w2; tile -= MT_TOT; }

    const int t    = threadIdx.x;
    const int lane = t & 63;
    const int wv   = t >> 6;
    const float* tb = src + (size_t)tile * 16 * D_DIM;

    // thread t's fixed pack-target for each row: chunk kt, slot-base, sub
    const int kt  = t >> 3;               // [0,32): chunk (k/32)
    const int s0  = 16 * ((t & 7) >> 1);  // 16*q, q = (k%32)/8
    const int sub = (t & 1) * 4;          // ushort offset inside 16B granule
    const int xs  = kt & 7;               // bank swizzle key

    #pragma unroll 4
    for (int i = 0; i < 16; ++i) {
        const float4 v = *(const float4*)(tb + i * D_DIM + t * 4);
        float ls = v.x*v.x + v.y*v.y + v.z*v.z + v.w*v.w;

        ushort u[4]; __hip_bfloat16 h;
        h = __float2bfloat16(v.x); u[0] = *(const ushort*)&h;
        h = __float2bfloat16(v.y); u[1] = *(const ushort*)&h;
        h = __float2bfloat16(v.z); u[2] = *(const ushort*)&h;
        h = __float2bfloat16(v.w); u[3] = *(const ushort*)&h;
        const int sp = (i + s0) ^ xs;     // swizzled slot [0,64)
        *(us4*)(L + kt * 512 + sp * 8 + sub) = *(const us4*)u;

        ls += __shfl_xor(ls, 1,  64);
        ls += __shfl_xor(ls, 2,  64);
        ls += __shfl_xor(ls, 4,  64);
        ls += __shfl_xor(ls, 8,  64);
        ls += __shfl_xor(ls, 16, 64);
        ls += __shfl_xor(ls, 32, 64);
        if (lane == 0)
            atomicAdd(norm + tile * 16 + i, ls * (1.0f / (float)D_DIM));
    }
    __syncthreads();

    // readout: wave w streams chunks w*8..w*8+7, 1 KB contiguous each
    ushort* dchunk = dst + (size_t)tile * KT32 * 512;
    #pragma unroll
    for (int j = 0; j < 8; ++j) {
        const int c = wv * 8 + j;
        const bf16x8 g = *(const bf16x8*)(L + c * 512 + (lane ^ (c & 7)) * 8);
        *(bf16x8*)(dchunk + (size_t)c * 512 + lane * 8) = g;
    }
}

// ---------------------------------------------------------------------------
// gemm_tb (verified R2, reverted unchanged): 128x128 tile, 4 waves 2x2,
// BK=32, TRIPLE-buffered LDS (3 x 16 KB = 48 KB -> 3 blocks/CU, 12 waves/CU).
// Counted vmcnt(4) never drained to 0 (T4); setprio around the 16-MFMA
// cluster (T5); stage kt+2 into the buffer freed at kt-1. Cross-block TLP
// (3 blocks/CU) hides barrier stalls and the epilogue.
// ---------------------------------------------------------------------------
__global__ __launch_bounds__(256, 3) void gemm_tb(
        const ushort* __restrict__ Apk, const ushort* __restrict__ Bpk,
        const float* __restrict__ x2, const float* __restrict__ w2,
        float* __restrict__ out) {
    __shared__ ushort As[3 * 4096];   // 24 KB: 3 bufs x 8 tiles x 512
    __shared__ ushort Bs[3 * 4096];   // 24 KB

    const int tid  = threadIdx.x;
    const int lane = tid & 63;
    const int wv   = tid >> 6;          // [0,4)

    const int wid = (blockIdx.x & 7) * 256 + (blockIdx.x >> 3);  // XCD slab
    const int bm  = wid >> 4;           // [0,128)
    const int bn  = wid & 15;           // [0,16)

    const ushort* aSrc = Apk + ((size_t)(bm * 8) * KT32) * 512 + lane * 8;
    const ushort* bSrc = Bpk + ((size_t)(bn * 8) * KT32) * 512 + lane * 8;

    const ushort* aRd = As + (wv >> 1) * 2048 + lane * 8;   // tiles (wv>>1)*4+mi
    const ushort* bRd = Bs + (wv & 1) * 2048 + lane * 8;    // tiles (wv&1)*4+ni

    const int t0 = wv, t1 = wv + 4;

#define STAGE(ktc, bufO) do { \
    __builtin_amdgcn_global_load_lds( \
        (const AS1 void*)(aSrc + ((size_t)t0 * KT32 + (ktc)) * 512), \
        (AS3 void*)(As + (bufO) + t0 * 512), 16, 0, 0); \
    __builtin_amdgcn_global_load_lds( \
        (const AS1 void*)(aSrc + ((size_t)t1 * KT32 + (ktc)) * 512), \
        (AS3 void*)(As + (bufO) + t1 * 512), 16, 0, 0); \
    __builtin_amdgcn_global_load_lds( \
        (const AS1 void*)(bSrc + ((size_t)t0 * KT32 + (ktc)) * 512), \
        (AS3 void*)(Bs + (bufO) + t0 * 512), 16, 0, 0); \
    __builtin_amdgcn_global_load_lds( \
        (const AS1 void*)(bSrc + ((size_t)t1 * KT32 + (ktc)) * 512), \
        (AS3 void*)(Bs + (bufO) + t1 * 512), 16, 0, 0); \
  } while (0)

    f32x4 acc[4][4];
    #pragma unroll
    for (int mi = 0; mi < 4; ++mi)
        #pragma unroll
        for (int ni = 0; ni < 4; ++ni)
            acc[mi][ni] = (f32x4){0.f, 0.f, 0.f, 0.f};

    // ---- prologue: stage kt=0 -> buf0, kt=1 -> buf1 (8 loads in flight) ----
    STAGE(0, 0);
    STAGE(1, 4096);
    VMCNT(4);        // kt=0's 4 chunks landed; kt=1's 4 stay in flight
    BARRIER;

    int curO = 0, nxtO = 4096, stgO = 8192;   // rotating buffer offsets
    for (int kt = 0; kt < KT32; ++kt) {
        bf16x8 a[4], b[4];
        #pragma unroll
        for (int mi = 0; mi < 4; ++mi)
            a[mi] = *(const bf16x8*)(aRd + curO + mi * 512);
        #pragma unroll
        for (int ni = 0; ni < 4; ++ni)
            b[ni] = *(const bf16x8*)(bRd + curO + ni * 512);

        STAGE((kt + 2) & 31, stgO);   // into buffer freed at kt-1

        VMCNT(4);    // kt+1's 4 landed (issued one full phase ago); 4 in flight
        BARRIER;     // all waves' kt+1 chunks visible -> next phase safe
        LGKM0;
        PRIO1;
        #pragma unroll
        for (int mi = 0; mi < 4; ++mi)
            #pragma unroll
            for (int ni = 0; ni < 4; ++ni)
                acc[mi][ni] = __builtin_amdgcn_mfma_f32_16x16x32_bf16(
                    a[mi], b[ni], acc[mi][ni], 0, 0, 0);
        PRIO0;
        BARRIER;     // reads of buf(cur) done before anyone stages into it

        const int t = curO; curO = nxtO; nxtO = stgO; stgO = t;
    }

    // ---- epilogue: C/D layout col=lane&15, row=(lane>>4)*4+reg (m89) ----
    const float scale = 2.0f / (float)D_DIM;
    const int rsel = lane & 15;
    const int quad = lane >> 4;
    const int mT0  = bm * 8 + (wv >> 1) * 4;
    const int nT0  = bn * 8 + (wv & 1) * 4;
    const int row0 = mT0 * 16 + quad * 4;
    const int col0 = nT0 * 16 + rsel;

    float x2r[4][4];
    #pragma unroll
    for (int mi = 0; mi < 4; ++mi)
        #pragma unroll
        for (int r = 0; r < 4; ++r)
            x2r[mi][r] = x2[row0 + mi * 16 + r];

    #pragma unroll
    for (int ni = 0; ni < 4; ++ni) {
        const int c = col0 + ni * 16;
        const float wc = w2[c];
        #pragma unroll
        for (int mi = 0; mi < 4; ++mi) {
            #pragma unroll
            for (int r = 0; r < 4; ++r) {
                const int rr = row0 + mi * 16 + r;
                out[(size_t)rr * C_DIM + c] = acc[mi][ni][r] * scale - x2r[mi][r] - wc;
            }
        }
    }
#undef STAGE
}

// ---------------------------------------------------------------------------
extern "C" void kernel_launch(void* const* d_in, const int* in_sizes, int n_in,
                              void* d_out, int out_size, void* d_ws, size_t ws_size,
                              hipStream_t stream) {
    const float* x = (const float*)d_in[0];   // [B, D] fp32
    const float* W = (const float*)d_in[1];   // [C, D] fp32
    float* out = (float*)d_out;               // [B, C] fp32

    // ws: Apk (32 MB bf16 packed) | Bpk (4 MB) | x2 (64 KB) | w2 (8 KB)
    char* ws = (char*)d_ws;
    ushort* Apk = (ushort*)ws;
    ushort* Bpk = (ushort*)(ws + (size_t)B_ROWS * D_DIM * sizeof(ushort));
    float*  x2  = (float*)(ws + (size_t)(B_ROWS + C_DIM) * D_DIM * sizeof(ushort));
    float*  w2  = x2 + B_ROWS;

    hipMemsetAsync(x2, 0, (B_ROWS + C_DIM) * sizeof(float), stream);

    pack_norm2<<<MT_TOT + NT_TOT, 256, 0, stream>>>(
        x, W, Apk, Bpk, x2, w2);

    gemm_tb<<<(B_ROWS / 128) * (C_DIM / 128), 256, 0, stream>>>(
        Apk, Bpk, x2, w2, out);
}